// Round 3
// baseline (1029.764 us; speedup 1.0000x reference)
//
#include <hip/hip_runtime.h>

#define BB 8
#define NN 200000
#define HH 480
#define WW 640
#define HWSZ (HH * WW)
#define BH 6                 // rows per slice
#define NSL (HH / BH)        // 80 slices per image

// ---------------------------------------------------------------------------
// Stage 1: per-event warp for one tref.
// payload[b][e] = {wy, wx, tw_signed, 0}; bidx[b][e] = clamp(floor(ty/BH),-1,80)+1
// ---------------------------------------------------------------------------
__global__ void prepass(const float4* __restrict__ ev,   // [B*N] (ts,y,x,p=+-1)
                        const float*  __restrict__ flow, // [B,2,H,W]
                        float4* __restrict__ pay,
                        unsigned char* __restrict__ bidx,
                        float tref) {
    int gid = blockIdx.x * blockDim.x + threadIdx.x;
    if (gid >= BB * NN) return;
    int b = gid / NN;

    float4 e = ev[gid];
    int gpix = (int)(e.y * (float)WW + e.z);
    const float* fb = flow + (size_t)b * 2 * HWSZ;
    float fx = fb[gpix];
    float fy = fb[HWSZ + gpix];

    float dt = tref - e.x;
    float wy = e.y + dt * fy * 640.0f;     // flow_scaling = 640
    float wx = e.z + dt * fx * 640.0f;
    float tw = (tref == 1.0f) ? e.x : (1.0f - e.x);
    float tws = tw * e.w;                  // sign encodes polarity (e.w = +-1)

    pay[gid] = make_float4(wy, wx, tws, 0.0f);

    float ty = floorf(wy);
    int bi = (int)floorf(ty * (1.0f / (float)BH));
    bi = max(-1, min(NSL, bi));            // [-1, 80]
    bidx[gid] = (unsigned char)(bi + 1);   // 0..81
}

// ---------------------------------------------------------------------------
// Block-reduce helper
// ---------------------------------------------------------------------------
__device__ __forceinline__ void block_reduce_add(float v, float* out) {
    #pragma unroll
    for (int off = 32; off > 0; off >>= 1)
        v += __shfl_down(v, off, 64);
    __shared__ float ls[4];
    int lane = threadIdx.x & 63;
    int wid  = threadIdx.x >> 6;
    if (lane == 0) ls[wid] = v;
    __syncthreads();
    if (threadIdx.x == 0)
        atomicAdd(out, ls[0] + ls[1] + ls[2] + ls[3]);
}

// ---------------------------------------------------------------------------
// Stage 2: one block per (batch, slice). LDS f32 accumulation + fused ratio.
// Accept events with bidx-1 in {s-1, s}  (i.e. stored byte in {s, s+1}).
// ---------------------------------------------------------------------------
__global__ void __launch_bounds__(256, 2) slice_scan(
        const float4* __restrict__ pay,
        const unsigned char* __restrict__ bidx,
        float* __restrict__ out) {
    __shared__ float acc[BH * WW * 4];     // [row][col][pol][{w,wt}] = 60 KB

    int b = blockIdx.x & 7;                // XCD-affinity: batch b -> XCD b
    int s = blockIdx.x >> 3;               // slice 0..79
    int r0 = s * BH;

    for (int i = threadIdx.x; i < BH * WW * 4; i += 256) acc[i] = 0.0f;
    __syncthreads();

    const size_t base = (size_t)b * NN;
    const uint4* pre = (const uint4*)(bidx + base);
    const float4* pb = pay + base;
    const int nchunk = NN / 16;            // 12500
    unsigned int us = (unsigned int)s;
    unsigned int rep_s  = us * 0x01010101u;
    unsigned int rep_s1 = rep_s + 0x01010101u;

    for (int c = threadIdx.x; c < nchunk; c += 256) {
        uint4 v = pre[c];
        #pragma unroll
        for (int wdi = 0; wdi < 4; ++wdi) {
            unsigned int w = (wdi == 0) ? v.x : (wdi == 1) ? v.y : (wdi == 2) ? v.z : v.w;
            // exact "word contains byte == s or byte == s+1" test
            unsigned int d0 = w ^ rep_s;
            unsigned int d1 = w ^ rep_s1;
            unsigned int hz = (((d0 - 0x01010101u) & ~d0) |
                               ((d1 - 0x01010101u) & ~d1)) & 0x80808080u;
            if (hz == 0) continue;
            #pragma unroll
            for (int j = 0; j < 4; ++j) {
                unsigned int byte = (w >> (8 * j)) & 0xffu;
                if (byte - us > 1u) continue;       // byte in {s, s+1}
                int e = c * 16 + wdi * 4 + j;
                float4 p = pb[e];
                float wy = p.x, wx = p.y;
                int   pol = (int)(__float_as_uint(p.z) >> 31);
                float tw  = fabsf(p.z);
                float ty = floorf(wy), lx = floorf(wx);
                float ry = wy - ty,    rx = wx - lx;
                int ity = (int)ty, ilx = (int)lx;
                #pragma unroll
                for (int dy = 0; dy < 2; ++dy) {
                    int iy = ity + dy;
                    if (iy < r0 || iy >= r0 + BH) continue;
                    float wyw = dy ? ry : 1.0f - ry;
                    #pragma unroll
                    for (int dx = 0; dx < 2; ++dx) {
                        int ix = ilx + dx;
                        if (ix < 0 || ix >= WW) continue;
                        float wgt = wyw * (dx ? rx : 1.0f - rx);
                        int a = (((iy - r0) * WW + ix) * 2 + pol) * 2;
                        atomicAdd(&acc[a],     wgt);        // ds_add_f32
                        atomicAdd(&acc[a + 1], wgt * tw);
                    }
                }
            }
        }
    }
    __syncthreads();

    // fused ratio reduce over this slice's pixels
    float sum = 0.0f;
    for (int i = threadIdx.x; i < BH * WW * 2; i += 256) {
        float wv = acc[i * 2], wt = acc[i * 2 + 1];
        float r = wt / (wv + 1e-9f);
        sum += r * r;
    }
    block_reduce_add(sum, out);
}

// ---------------------------------------------------------------------------
// Stage 3: Charbonnier smoothness over flow
// ---------------------------------------------------------------------------
__global__ void smooth_reduce(const float* __restrict__ flow,
                              float* __restrict__ out) {
    const size_t total = (size_t)BB * 2 * HWSZ;
    float s = 0.0f;
    for (size_t i = (size_t)blockIdx.x * blockDim.x + threadIdx.x; i < total;
         i += (size_t)gridDim.x * blockDim.x) {
        int w = (int)(i % WW);
        int h = (int)((i / WW) % HH);
        float v = flow[i];
        if (h < HH - 1) {
            float d = v - flow[i + WW];
            s += sqrtf(d * d + 1e-6f);
        }
        if (w < WW - 1) {
            float d = v - flow[i + 1];
            s += sqrtf(d * d + 1e-6f);
        }
    }
    block_reduce_add(s, out);
}

extern "C" void kernel_launch(void* const* d_in, const int* in_sizes, int n_in,
                              void* d_out, int out_size, void* d_ws, size_t ws_size,
                              hipStream_t stream) {
    const float*  flow = (const float*)d_in[0];   // [B,2,H,W]
    const float4* ev   = (const float4*)d_in[1];  // [B,N,4]
    float* out = (float*)d_out;

    // ws layout: payload float4 [B*N] (25.6 MB) | bidx u8 [B*N] (1.6 MB)
    float4* pay = (float4*)d_ws;
    unsigned char* bidx = (unsigned char*)d_ws + (size_t)BB * NN * sizeof(float4);

    hipMemsetAsync(out, 0, sizeof(float), stream);

    const int ppBlocks = (BB * NN + 255) / 256;
    const int slBlocks = 8 * NSL;                 // 640

    // tref = 1 pass, then tref = 0 pass (payload buffers reused)
    for (int t = 0; t < 2; ++t) {
        float tref = (t == 0) ? 1.0f : 0.0f;
        prepass<<<ppBlocks, 256, 0, stream>>>(ev, flow, pay, bidx, tref);
        slice_scan<<<slBlocks, 256, 0, stream>>>(pay, bidx, out);
    }
    smooth_reduce<<<1024, 256, 0, stream>>>(flow, out);
}

// Round 4
// 610.126 us; speedup vs baseline: 1.6878x; 1.6878x over previous
//
#include <hip/hip_runtime.h>

#define BB 8
#define NN 200000
#define HH 480
#define WW 640
#define HWSZ (HH * WW)
#define BH 4                        // rows per slice
#define NSL (HH / BH)               // 120 slices
#define EPB 2048                    // events per block (K1/K3)
#define BPB ((NN + EPB - 1) / EPB)  // 98 blocks per batch
#define SCAN_N (BB * NSL * BPB)     // 94080 histogram cells
#define CAP 2250000                 // sorted-entry capacity (exp ~2.0M)

// ---------------------------------------------------------------------------
// Common warp math. fmaf forms are identical in K1/K3 so slice codes match.
// ---------------------------------------------------------------------------
__device__ __forceinline__ void warp_event(
    const float4 e, const float* __restrict__ fb, float tref,
    float& wy, float& wx, float& tws, int& sfirst, bool& dual) {
    int gpix = (int)(e.y * (float)WW + e.z);
    float fx = fb[gpix];
    float fy = fb[HWSZ + gpix];
    float dt = tref - e.x;
    wy = fmaf(dt * fy, 640.0f, e.y);     // flow_scaling = 640
    wx = fmaf(dt * fx, 640.0f, e.z);
    float tw = (tref == 1.0f) ? e.x : (1.0f - e.x);
    tws = tw * e.w;                      // e.w = +-1 encodes polarity
    sfirst = -1; dual = false;
    if (wx < -1.0f || wx >= (float)WW) return;         // all corners x-OOB
    if (wy < -2.0f || wy >= (float)HH + 1.0f) return;  // all corners y-OOB
    int ity = (int)floorf(wy);
    int r1 = ity + 1;
    bool v0 = (ity >= 0 && ity < HH);
    bool v1 = (r1 >= 0 && r1 < HH);
    if (v0) {
        sfirst = ity >> 2;
        dual = v1 && ((r1 >> 2) != sfirst);   // straddle -> also slice+1
    } else if (v1) {
        sfirst = r1 >> 2;                     // ity == -1 case
    }
}

// ---------------------------------------------------------------------------
// K1: per-block LDS histogram over slices -> hist[b][slice][block]
// also stores 1-byte slice code per event for exact K3 consistency.
// ---------------------------------------------------------------------------
__global__ void __launch_bounds__(256) prep_hist(
        const float4* __restrict__ ev, const float* __restrict__ flow,
        unsigned int* __restrict__ hist, unsigned char* __restrict__ code,
        float tref) {
    __shared__ unsigned int h[NSL];
    int b  = blockIdx.x / BPB;
    int bb = blockIdx.x % BPB;
    for (int i = threadIdx.x; i < NSL; i += 256) h[i] = 0;
    __syncthreads();

    const float*  fb  = flow + (size_t)b * 2 * HWSZ;
    const float4* evb = ev   + (size_t)b * NN;
    unsigned char* cb = code + (size_t)b * NN;
    int base = bb * EPB;
    #pragma unroll
    for (int k = 0; k < EPB / 256; ++k) {
        int e = base + k * 256 + threadIdx.x;
        if (e < NN) {
            float wy, wx, tws; int s0; bool dual;
            warp_event(evb[e], fb, tref, wy, wx, tws, s0, dual);
            unsigned char c = 0;
            if (s0 >= 0) {
                c = (unsigned char)(s0 + 1) | (dual ? 0x80 : 0);
                atomicAdd(&h[s0], 1u);
                if (dual) atomicAdd(&h[s0 + 1], 1u);
            }
            cb[e] = c;
        }
    }
    __syncthreads();
    for (int s = threadIdx.x; s < NSL; s += 256)
        hist[((size_t)b * NSL + s) * BPB + bb] = h[s];
}

// ---------------------------------------------------------------------------
// K2: single-block exclusive scan of hist[0..SCAN_N), total -> hist[SCAN_N]
// ---------------------------------------------------------------------------
__global__ void __launch_bounds__(1024) scan_hist(unsigned int* __restrict__ hist) {
    __shared__ unsigned int wsum[16];
    __shared__ unsigned int carry_s;
    if (threadIdx.x == 0) carry_s = 0;
    __syncthreads();
    int lane = threadIdx.x & 63, wid = threadIdx.x >> 6;
    for (unsigned int base = 0; base < SCAN_N; base += 8192) {
        unsigned int i0 = base + threadIdx.x * 8;
        unsigned int v[8], sum = 0;
        #pragma unroll
        for (int j = 0; j < 8; ++j) {
            unsigned int i = i0 + j;
            v[j] = (i < SCAN_N) ? hist[i] : 0u;
            sum += v[j];
        }
        unsigned int inc = sum;
        #pragma unroll
        for (int off = 1; off < 64; off <<= 1) {
            unsigned int t = __shfl_up(inc, off, 64);
            if (lane >= off) inc += t;
        }
        if (lane == 63) wsum[wid] = inc;
        __syncthreads();
        if (wid == 0) {
            unsigned int wv = (lane < 16) ? wsum[lane] : 0u;
            #pragma unroll
            for (int off = 1; off < 16; off <<= 1) {
                unsigned int t = __shfl_up(wv, off, 64);
                if (lane >= off) wv += t;
            }
            if (lane < 16) wsum[lane] = wv;
        }
        __syncthreads();
        unsigned int wbase = (wid == 0) ? 0u : wsum[wid - 1];
        unsigned int carry = carry_s;
        unsigned int excl = carry + wbase + (inc - sum);
        #pragma unroll
        for (int j = 0; j < 8; ++j) {
            unsigned int i = i0 + j;
            if (i < SCAN_N) hist[i] = excl;
            excl += v[j];
        }
        __syncthreads();
        if (threadIdx.x == 1023) carry_s = carry + wsum[15];
        __syncthreads();
    }
    if (threadIdx.x == 0) hist[SCAN_N] = carry_s;
}

// ---------------------------------------------------------------------------
// K3: recompute warp, place payload at exact sorted position.
// ---------------------------------------------------------------------------
__global__ void __launch_bounds__(256) scatter_sorted(
        const float4* __restrict__ ev, const float* __restrict__ flow,
        const unsigned int* __restrict__ scan, const unsigned char* __restrict__ code,
        float4* __restrict__ sorted, float tref) {
    __shared__ unsigned int bases[NSL];
    __shared__ unsigned int cnt[NSL];
    int b  = blockIdx.x / BPB;
    int bb = blockIdx.x % BPB;
    for (int i = threadIdx.x; i < NSL; i += 256) {
        bases[i] = scan[((size_t)b * NSL + i) * BPB + bb];
        cnt[i] = 0;
    }
    __syncthreads();

    const float*  fb  = flow + (size_t)b * 2 * HWSZ;
    const float4* evb = ev   + (size_t)b * NN;
    const unsigned char* cb = code + (size_t)b * NN;
    int base = bb * EPB;
    #pragma unroll
    for (int k = 0; k < EPB / 256; ++k) {
        int e = base + k * 256 + threadIdx.x;
        if (e < NN) {
            unsigned char c = cb[e];
            if (c) {
                float wy, wx, tws; int s0d; bool duald;
                warp_event(evb[e], fb, tref, wy, wx, tws, s0d, duald);
                int s = (c & 0x7f) - 1;
                float4 p = make_float4(wy, wx, tws, 0.0f);
                unsigned int pos = bases[s] + atomicAdd(&cnt[s], 1u);
                sorted[pos] = p;
                if (c & 0x80) {
                    pos = bases[s + 1] + atomicAdd(&cnt[s + 1], 1u);
                    sorted[pos] = p;
                }
            }
        }
    }
}

// ---------------------------------------------------------------------------
// K4: one block per (batch, slice); contiguous reads, LDS f32 accumulate,
// fused ratio-square reduce.
// ---------------------------------------------------------------------------
__global__ void __launch_bounds__(256) slice_accum(
        const float4* __restrict__ sorted, const unsigned int* __restrict__ scan,
        float* __restrict__ out) {
    __shared__ float acc[BH * WW * 4];   // [row][col][pol][{w,wt}] = 40 KB
    int b = blockIdx.x & 7;              // XCD-affinity
    int s = blockIdx.x >> 3;
    for (int i = threadIdx.x; i < BH * WW * 4; i += 256) acc[i] = 0.0f;
    __syncthreads();

    unsigned int beg = scan[((size_t)b * NSL + s) * BPB];
    unsigned int end = scan[((size_t)b * NSL + s + 1) * BPB];
    int r0 = s * BH;

    for (unsigned int i = beg + threadIdx.x; i < end; i += 256) {
        float4 p = sorted[i];
        float wy = p.x, wx = p.y;
        int   pol = (int)(__float_as_uint(p.z) >> 31);
        float tw  = fabsf(p.z);
        float ty = floorf(wy), lxf = floorf(wx);
        float ry = wy - ty,    rx = wx - lxf;
        int ity = (int)ty, ilx = (int)lxf;
        #pragma unroll
        for (int dy = 0; dy < 2; ++dy) {
            int r = ity + dy;
            if (r < r0 || r >= r0 + BH) continue;    // clip to this slice
            float wyw = dy ? ry : 1.0f - ry;
            #pragma unroll
            for (int dx = 0; dx < 2; ++dx) {
                int ix = ilx + dx;
                if (ix < 0 || ix >= WW) continue;
                float wgt = wyw * (dx ? rx : 1.0f - rx);
                int a = (((r - r0) * WW + ix) * 2 + pol) * 2;
                atomicAdd(&acc[a],     wgt);
                atomicAdd(&acc[a + 1], wgt * tw);
            }
        }
    }
    __syncthreads();

    float sum = 0.0f;
    for (int i = threadIdx.x; i < BH * WW * 2; i += 256) {
        float w = acc[2 * i], wt = acc[2 * i + 1];
        float r = wt / (w + 1e-9f);
        sum += r * r;
    }
    #pragma unroll
    for (int off = 32; off > 0; off >>= 1)
        sum += __shfl_down(sum, off, 64);
    __syncthreads();                       // done reading acc
    int lane = threadIdx.x & 63, wid = threadIdx.x >> 6;
    if (lane == 0) acc[wid] = sum;
    __syncthreads();
    if (threadIdx.x == 0)
        atomicAdd(out, acc[0] + acc[1] + acc[2] + acc[3]);
}

// ---------------------------------------------------------------------------
// K5: Charbonnier smoothness over flow
// ---------------------------------------------------------------------------
__global__ void smooth_reduce(const float* __restrict__ flow,
                              float* __restrict__ out) {
    const size_t total = (size_t)BB * 2 * HWSZ;
    float s = 0.0f;
    for (size_t i = (size_t)blockIdx.x * blockDim.x + threadIdx.x; i < total;
         i += (size_t)gridDim.x * blockDim.x) {
        int w = (int)(i % WW);
        int h = (int)((i / WW) % HH);
        float v = flow[i];
        if (h < HH - 1) {
            float d = v - flow[i + WW];
            s += sqrtf(d * d + 1e-6f);
        }
        if (w < WW - 1) {
            float d = v - flow[i + 1];
            s += sqrtf(d * d + 1e-6f);
        }
    }
    #pragma unroll
    for (int off = 32; off > 0; off >>= 1)
        s += __shfl_down(s, off, 64);
    __shared__ float ls[4];
    int lane = threadIdx.x & 63, wid = threadIdx.x >> 6;
    if (lane == 0) ls[wid] = s;
    __syncthreads();
    if (threadIdx.x == 0)
        atomicAdd(out, ls[0] + ls[1] + ls[2] + ls[3]);
}

extern "C" void kernel_launch(void* const* d_in, const int* in_sizes, int n_in,
                              void* d_out, int out_size, void* d_ws, size_t ws_size,
                              hipStream_t stream) {
    const float*  flow = (const float*)d_in[0];   // [B,2,H,W]
    const float4* ev   = (const float4*)d_in[1];  // [B,N,4]
    float* out = (float*)d_out;

    // ws layout: sorted float4[CAP] (36.0 MB) | hist u32[SCAN_N+1] (376 KB)
    //          | code u8[B*N] (1.6 MB)   -> total ~38.0 MB
    float4* sorted = (float4*)d_ws;
    unsigned int* hist = (unsigned int*)((char*)d_ws + (size_t)CAP * sizeof(float4));
    unsigned char* code = (unsigned char*)(hist + (SCAN_N + 1));

    hipMemsetAsync(out, 0, sizeof(float), stream);

    const int pBlocks = BB * BPB;    // 784
    const int aBlocks = BB * NSL;    // 960

    for (int t = 0; t < 2; ++t) {
        float tref = (t == 0) ? 1.0f : 0.0f;
        prep_hist<<<pBlocks, 256, 0, stream>>>(ev, flow, hist, code, tref);
        scan_hist<<<1, 1024, 0, stream>>>(hist);
        scatter_sorted<<<pBlocks, 256, 0, stream>>>(ev, flow, hist, code, sorted, tref);
        slice_accum<<<aBlocks, 256, 0, stream>>>(sorted, hist, out);
    }
    smooth_reduce<<<1024, 256, 0, stream>>>(flow, out);
}

// Round 5
// 232.633 us; speedup vs baseline: 4.4266x; 2.6227x over previous
//
#include <hip/hip_runtime.h>
#include <hip/hip_fp16.h>

#define BB 8
#define NN 200000
#define HH 480
#define WW 640
#define HWSZ (HH * WW)
#define BH 4                        // rows per slice
#define NSL (HH / BH)               // 120 slices
#define EPB 2048                    // events per block in warp_place
#define BPB ((NN + EPB - 1) / EPB)  // 98 blocks per batch
#define STRIDE 3584                 // arena slots per (b,slice); mean ~2083

// ---------------------------------------------------------------------------
// K0: flow interleave (f32x2 -> half2, L2-friendly gather target) fused with
// Charbonnier smoothness reduction.
// ---------------------------------------------------------------------------
__global__ void __launch_bounds__(256) flow_prep(
        const float* __restrict__ flow, __half2* __restrict__ fxy,
        float* __restrict__ out) {
    const int total = BB * HWSZ;
    float s = 0.0f;
    for (int i = blockIdx.x * 256 + threadIdx.x; i < total;
         i += gridDim.x * 256) {
        int b = i / HWSZ, pix = i % HWSZ;
        const float* fb = flow + (size_t)b * 2 * HWSZ;
        float f0 = fb[pix], f1 = fb[HWSZ + pix];
        fxy[i] = __floats2half2_rn(f0, f1);
        int w = pix % WW, h = pix / WW;
        if (h < HH - 1) {
            float d0 = f0 - fb[pix + WW];
            float d1 = f1 - fb[HWSZ + pix + WW];
            s += sqrtf(d0 * d0 + 1e-6f) + sqrtf(d1 * d1 + 1e-6f);
        }
        if (w < WW - 1) {
            float d0 = f0 - fb[pix + 1];
            float d1 = f1 - fb[HWSZ + pix + 1];
            s += sqrtf(d0 * d0 + 1e-6f) + sqrtf(d1 * d1 + 1e-6f);
        }
    }
    #pragma unroll
    for (int off = 32; off > 0; off >>= 1)
        s += __shfl_down(s, off, 64);
    __shared__ float ls[4];
    int lane = threadIdx.x & 63, wid = threadIdx.x >> 6;
    if (lane == 0) ls[wid] = s;
    __syncthreads();
    if (threadIdx.x == 0)
        atomicAdd(out, ls[0] + ls[1] + ls[2] + ls[3]);
}

// ---------------------------------------------------------------------------
// K1: warp events, LDS histogram per slice, one global atomicAdd per touched
// slice to reserve a contiguous range, write 8B packed payloads into arena.
// payload: [qy:20 @38][qx:21 @17][pol:1 @16][qt:16 @0], coords (v+2)*2048.
// ---------------------------------------------------------------------------
__global__ void __launch_bounds__(256) warp_place(
        const float4* __restrict__ ev, const __half2* __restrict__ fxy,
        unsigned int* __restrict__ counters,
        unsigned long long* __restrict__ arena, float tref) {
    __shared__ unsigned int h[NSL];
    __shared__ unsigned int bases[NSL];
    int b     = blockIdx.x & 7;            // XCD-affinity: batch b -> XCD b
    int chunk = blockIdx.x >> 3;
    for (int i = threadIdx.x; i < NSL; i += 256) h[i] = 0;
    __syncthreads();

    const float4*  evb = ev  + (size_t)b * NN;
    const __half2* fb  = fxy + (size_t)b * HWSZ;
    int base = chunk * EPB;

    unsigned long long pay[8];
    int code[8];                           // 0 invalid; else (s0+1) | dual<<8
    #pragma unroll
    for (int k = 0; k < 8; ++k) {
        code[k] = 0;
        int e = base + k * 256 + threadIdx.x;
        if (e < NN) {
            float4 E = evb[e];
            int gpix = (int)(E.y * 640.0f + E.z);
            float2 f = __half22float2(fb[gpix]);
            float dt = tref - E.x;
            float wy = fmaf(dt * f.y, 640.0f, E.y);   // flow_scaling = 640
            float wx = fmaf(dt * f.x, 640.0f, E.z);
            if (wx >= -1.0f && wx < 640.0f && wy >= -2.0f && wy < 481.0f) {
                int ity = (int)floorf(wy);
                int r1 = ity + 1;
                bool v0 = (ity >= 0) && (ity < HH);
                bool v1 = (r1  >= 0) && (r1  < HH);
                int s0 = -1; bool dual = false;
                if (v0) { s0 = ity >> 2; dual = v1 && ((r1 >> 2) != s0); }
                else if (v1) s0 = r1 >> 2;
                if (s0 >= 0) {
                    code[k] = (s0 + 1) | (dual ? 0x100 : 0);
                    float tw = (tref == 1.0f) ? E.x : (1.0f - E.x);
                    unsigned int pol = (E.w < 0.0f) ? 1u : 0u;
                    unsigned int qy = (unsigned int)((wy + 2.0f) * 2048.0f);
                    unsigned int qx = (unsigned int)((wx + 2.0f) * 2048.0f);
                    unsigned int qt = (unsigned int)fmaf(tw, 65535.0f, 0.5f);
                    pay[k] = ((unsigned long long)qy << 38)
                           | ((unsigned long long)qx << 17)
                           | ((unsigned long long)pol << 16)
                           | (unsigned long long)qt;
                    atomicAdd(&h[s0], 1u);
                    if (dual) atomicAdd(&h[s0 + 1], 1u);
                }
            }
        }
    }
    __syncthreads();
    for (int s = threadIdx.x; s < NSL; s += 256) {
        unsigned int c = h[s];
        bases[s] = c ? atomicAdd(&counters[b * NSL + s], c) : 0u;
        h[s] = 0;                          // reuse as within-block cursor
    }
    __syncthreads();
    #pragma unroll
    for (int k = 0; k < 8; ++k) {
        if (code[k]) {
            int s = (code[k] & 0xff) - 1;
            unsigned int off = bases[s] + atomicAdd(&h[s], 1u);
            if (off < STRIDE)
                arena[((size_t)(b * NSL + s)) * STRIDE + off] = pay[k];
            if (code[k] & 0x100) {
                off = bases[s + 1] + atomicAdd(&h[s + 1], 1u);
                if (off < STRIDE)
                    arena[((size_t)(b * NSL + s + 1)) * STRIDE + off] = pay[k];
            }
        }
    }
}

// ---------------------------------------------------------------------------
// K2: one block per (batch, slice); contiguous 8B reads, decode, LDS f32
// accumulate [row][col][pol][{w,wt}], fused ratio-square reduce.
// ---------------------------------------------------------------------------
__global__ void __launch_bounds__(256) slice_accum(
        const unsigned long long* __restrict__ arena,
        const unsigned int* __restrict__ counters, float* __restrict__ out) {
    __shared__ float acc[BH * WW * 4];     // 40 KB
    int b = blockIdx.x & 7;                // XCD-affinity
    int s = blockIdx.x >> 3;
    for (int i = threadIdx.x; i < BH * WW * 4; i += 256) acc[i] = 0.0f;
    __syncthreads();

    unsigned int cnt = counters[b * NSL + s];
    if (cnt > STRIDE) cnt = STRIDE;
    const unsigned long long* cell = arena + ((size_t)(b * NSL + s)) * STRIDE;
    int r0 = s * BH;

    for (unsigned int i = threadIdx.x; i < cnt; i += 256) {
        unsigned long long p = cell[i];
        float tw = (float)(unsigned int)(p & 0xFFFFu) * (1.0f / 65535.0f);
        int  pol = (int)((p >> 16) & 1u);
        float wx = (float)(unsigned int)((p >> 17) & 0x1FFFFFu) * (1.0f / 2048.0f) - 2.0f;
        float wy = (float)(unsigned int)((p >> 38) & 0xFFFFFu)  * (1.0f / 2048.0f) - 2.0f;
        float fy = floorf(wy), fx = floorf(wx);
        float ry = wy - fy,    rx = wx - fx;
        int ity = (int)fy, ilx = (int)fx;
        #pragma unroll
        for (int dy = 0; dy < 2; ++dy) {
            int r = ity + dy;
            if (r < r0 || r >= r0 + BH) continue;   // clip rows to slice
            float wyw = dy ? ry : 1.0f - ry;
            #pragma unroll
            for (int dx = 0; dx < 2; ++dx) {
                int ix = ilx + dx;
                if (ix < 0 || ix >= WW) continue;
                float wgt = wyw * (dx ? rx : 1.0f - rx);
                int a = (((r - r0) * WW + ix) * 2 + pol) * 2;
                atomicAdd(&acc[a],     wgt);
                atomicAdd(&acc[a + 1], wgt * tw);
            }
        }
    }
    __syncthreads();

    float sum = 0.0f;
    for (int i = threadIdx.x; i < BH * WW * 2; i += 256) {
        float w = acc[2 * i], wt = acc[2 * i + 1];
        float r = wt / (w + 1e-9f);
        sum += r * r;
    }
    #pragma unroll
    for (int off = 32; off > 0; off >>= 1)
        sum += __shfl_down(sum, off, 64);
    __syncthreads();                       // done reading acc
    int lane = threadIdx.x & 63, wid = threadIdx.x >> 6;
    if (lane == 0) acc[wid] = sum;
    __syncthreads();
    if (threadIdx.x == 0)
        atomicAdd(out, acc[0] + acc[1] + acc[2] + acc[3]);
}

extern "C" void kernel_launch(void* const* d_in, const int* in_sizes, int n_in,
                              void* d_out, int out_size, void* d_ws, size_t ws_size,
                              hipStream_t stream) {
    const float*  flow = (const float*)d_in[0];   // [B,2,H,W]
    const float4* ev   = (const float4*)d_in[1];  // [B,N,4]
    float* out = (float*)d_out;

    // ws: arena u64[8*120*3584] (27.5 MB) | fxy half2[B*HW] (9.83 MB)
    //   | counters u32[960] -> total ~37.4 MB
    unsigned long long* arena = (unsigned long long*)d_ws;
    __half2* fxy = (__half2*)((char*)d_ws +
                              (size_t)BB * NSL * STRIDE * sizeof(unsigned long long));
    unsigned int* counters = (unsigned int*)((char*)fxy +
                              (size_t)BB * HWSZ * sizeof(__half2));

    hipMemsetAsync(out, 0, sizeof(float), stream);

    flow_prep<<<1024, 256, 0, stream>>>(flow, fxy, out);

    const int pBlocks = BB * BPB;    // 784
    const int aBlocks = BB * NSL;    // 960

    for (int t = 0; t < 2; ++t) {
        float tref = (t == 0) ? 1.0f : 0.0f;
        hipMemsetAsync(counters, 0, BB * NSL * sizeof(unsigned int), stream);
        warp_place<<<pBlocks, 256, 0, stream>>>(ev, fxy, counters, arena, tref);
        slice_accum<<<aBlocks, 256, 0, stream>>>(arena, counters, out);
    }
}

// Round 6
// 165.117 us; speedup vs baseline: 6.2366x; 1.4089x over previous
//
#include <hip/hip_runtime.h>
#include <hip/hip_fp16.h>

#define BB 8
#define NN 200000
#define HH 480
#define WW 640
#define HWSZ (HH * WW)
#define BH 4                        // rows per slice
#define NSL (HH / BH)               // 120 slices
#define EPB 2048                    // events per block in warp_place
#define BPB ((NN + EPB - 1) / EPB)  // 98 blocks per batch
#define STRIDE 3584                 // arena slots per (b,slice); mean ~2083

// ---------------------------------------------------------------------------
// K0: flow interleave (f32x2 -> half2, L2-friendly gather target) fused with
// Charbonnier smoothness reduction.
// ---------------------------------------------------------------------------
__global__ void __launch_bounds__(256) flow_prep(
        const float* __restrict__ flow, __half2* __restrict__ fxy,
        float* __restrict__ out) {
    const int total = BB * HWSZ;
    float s = 0.0f;
    for (int i = blockIdx.x * 256 + threadIdx.x; i < total;
         i += gridDim.x * 256) {
        int b = i / HWSZ, pix = i % HWSZ;
        const float* fb = flow + (size_t)b * 2 * HWSZ;
        float f0 = fb[pix], f1 = fb[HWSZ + pix];
        fxy[i] = __floats2half2_rn(f0, f1);
        int w = pix % WW, h = pix / WW;
        if (h < HH - 1) {
            float d0 = f0 - fb[pix + WW];
            float d1 = f1 - fb[HWSZ + pix + WW];
            s += sqrtf(d0 * d0 + 1e-6f) + sqrtf(d1 * d1 + 1e-6f);
        }
        if (w < WW - 1) {
            float d0 = f0 - fb[pix + 1];
            float d1 = f1 - fb[HWSZ + pix + 1];
            s += sqrtf(d0 * d0 + 1e-6f) + sqrtf(d1 * d1 + 1e-6f);
        }
    }
    #pragma unroll
    for (int off = 32; off > 0; off >>= 1)
        s += __shfl_down(s, off, 64);
    __shared__ float ls[4];
    int lane = threadIdx.x & 63, wid = threadIdx.x >> 6;
    if (lane == 0) ls[wid] = s;
    __syncthreads();
    if (threadIdx.x == 0)
        atomicAdd(out, ls[0] + ls[1] + ls[2] + ls[3]);
}

// ---------------------------------------------------------------------------
// K1: warp events, LDS histogram per slice, one global atomicAdd per touched
// slice to reserve a contiguous range, write 8B packed payloads into arena.
// payload: [qy:20 @38][qx:21 @17][pol:1 @16][qt:16 @0], coords (v+2)*2048.
// ---------------------------------------------------------------------------
__global__ void __launch_bounds__(256) warp_place(
        const float4* __restrict__ ev, const __half2* __restrict__ fxy,
        unsigned int* __restrict__ counters,
        unsigned long long* __restrict__ arena, float tref) {
    __shared__ unsigned int h[NSL];
    __shared__ unsigned int bases[NSL];
    int b     = blockIdx.x & 7;            // XCD-affinity: batch b -> XCD b
    int chunk = blockIdx.x >> 3;
    for (int i = threadIdx.x; i < NSL; i += 256) h[i] = 0;
    __syncthreads();

    const float4*  evb = ev  + (size_t)b * NN;
    const __half2* fb  = fxy + (size_t)b * HWSZ;
    int base = chunk * EPB;

    unsigned long long pay[8];
    int code[8];                           // 0 invalid; else (s0+1) | dual<<8
    #pragma unroll
    for (int k = 0; k < 8; ++k) {
        code[k] = 0;
        int e = base + k * 256 + threadIdx.x;
        if (e < NN) {
            float4 E = evb[e];
            int gpix = (int)(E.y * 640.0f + E.z);
            float2 f = __half22float2(fb[gpix]);
            float dt = tref - E.x;
            float wy = fmaf(dt * f.y, 640.0f, E.y);   // flow_scaling = 640
            float wx = fmaf(dt * f.x, 640.0f, E.z);
            if (wx >= -1.0f && wx < 640.0f && wy >= -2.0f && wy < 481.0f) {
                int ity = (int)floorf(wy);
                int r1 = ity + 1;
                bool v0 = (ity >= 0) && (ity < HH);
                bool v1 = (r1  >= 0) && (r1  < HH);
                int s0 = -1; bool dual = false;
                if (v0) { s0 = ity >> 2; dual = v1 && ((r1 >> 2) != s0); }
                else if (v1) s0 = r1 >> 2;
                if (s0 >= 0) {
                    code[k] = (s0 + 1) | (dual ? 0x100 : 0);
                    float tw = (tref == 1.0f) ? E.x : (1.0f - E.x);
                    unsigned int pol = (E.w < 0.0f) ? 1u : 0u;
                    unsigned int qy = (unsigned int)((wy + 2.0f) * 2048.0f);
                    unsigned int qx = (unsigned int)((wx + 2.0f) * 2048.0f);
                    unsigned int qt = (unsigned int)fmaf(tw, 65535.0f, 0.5f);
                    pay[k] = ((unsigned long long)qy << 38)
                           | ((unsigned long long)qx << 17)
                           | ((unsigned long long)pol << 16)
                           | (unsigned long long)qt;
                    atomicAdd(&h[s0], 1u);
                    if (dual) atomicAdd(&h[s0 + 1], 1u);
                }
            }
        }
    }
    __syncthreads();
    for (int s = threadIdx.x; s < NSL; s += 256) {
        unsigned int c = h[s];
        bases[s] = c ? atomicAdd(&counters[b * NSL + s], c) : 0u;
        h[s] = 0;                          // reuse as within-block cursor
    }
    __syncthreads();
    #pragma unroll
    for (int k = 0; k < 8; ++k) {
        if (code[k]) {
            int s = (code[k] & 0xff) - 1;
            unsigned int off = bases[s] + atomicAdd(&h[s], 1u);
            if (off < STRIDE)
                arena[((size_t)(b * NSL + s)) * STRIDE + off] = pay[k];
            if (code[k] & 0x100) {
                off = bases[s + 1] + atomicAdd(&h[s + 1], 1u);
                if (off < STRIDE)
                    arena[((size_t)(b * NSL + s + 1)) * STRIDE + off] = pay[k];
            }
        }
    }
}

// ---------------------------------------------------------------------------
// K2: one block per (batch, slice); contiguous 8B reads, decode, LDS half2
// accumulate [row][col][pol] = {w, wt} via ds_pk_add_f16, fused ratio reduce.
// 512 threads: 20KB LDS -> ~30 waves/CU occupancy.
// ---------------------------------------------------------------------------
__global__ void __launch_bounds__(512) slice_accum(
        const unsigned long long* __restrict__ arena,
        const unsigned int* __restrict__ counters, float* __restrict__ out) {
    __shared__ __half2 acc[BH * WW * 2];   // [row][col][pol] {w,wt} = 20 KB
    int b = blockIdx.x & 7;                // XCD-affinity
    int s = blockIdx.x >> 3;
    for (int i = threadIdx.x; i < BH * WW * 2; i += 512)
        acc[i] = __half2(__float2half(0.0f), __float2half(0.0f));
    __syncthreads();

    unsigned int cnt = counters[b * NSL + s];
    if (cnt > STRIDE) cnt = STRIDE;
    const unsigned long long* cell = arena + ((size_t)(b * NSL + s)) * STRIDE;
    int r0 = s * BH;

    for (unsigned int i = threadIdx.x; i < cnt; i += 512) {
        unsigned long long p = cell[i];
        float tw = (float)(unsigned int)(p & 0xFFFFu) * (1.0f / 65535.0f);
        int  pol = (int)((p >> 16) & 1u);
        float wx = (float)(unsigned int)((p >> 17) & 0x1FFFFFu) * (1.0f / 2048.0f) - 2.0f;
        float wy = (float)(unsigned int)((p >> 38) & 0xFFFFFu)  * (1.0f / 2048.0f) - 2.0f;
        float fy = floorf(wy), fx = floorf(wx);
        float ry = wy - fy,    rx = wx - fx;
        int ity = (int)fy, ilx = (int)fx;
        #pragma unroll
        for (int dy = 0; dy < 2; ++dy) {
            int r = ity + dy;
            if (r < r0 || r >= r0 + BH) continue;   // clip rows to slice
            float wyw = dy ? ry : 1.0f - ry;
            #pragma unroll
            for (int dx = 0; dx < 2; ++dx) {
                int ix = ilx + dx;
                if (ix < 0 || ix >= WW) continue;
                float wgt = wyw * (dx ? rx : 1.0f - rx);
                int a = ((r - r0) * WW + ix) * 2 + pol;
                unsafeAtomicAdd(&acc[a], __floats2half2_rn(wgt, wgt * tw));
            }
        }
    }
    __syncthreads();

    float sum = 0.0f;
    for (int i = threadIdx.x; i < BH * WW * 2; i += 512) {
        float2 v = __half22float2(acc[i]);
        float r = v.y / (v.x + 1e-9f);
        sum += r * r;
    }
    #pragma unroll
    for (int off = 32; off > 0; off >>= 1)
        sum += __shfl_down(sum, off, 64);
    __shared__ float ls[8];
    int lane = threadIdx.x & 63, wid = threadIdx.x >> 6;
    if (lane == 0) ls[wid] = sum;
    __syncthreads();
    if (threadIdx.x == 0) {
        float t = 0.0f;
        #pragma unroll
        for (int k = 0; k < 8; ++k) t += ls[k];
        atomicAdd(out, t);
    }
}

extern "C" void kernel_launch(void* const* d_in, const int* in_sizes, int n_in,
                              void* d_out, int out_size, void* d_ws, size_t ws_size,
                              hipStream_t stream) {
    const float*  flow = (const float*)d_in[0];   // [B,2,H,W]
    const float4* ev   = (const float4*)d_in[1];  // [B,N,4]
    float* out = (float*)d_out;

    // ws: arena u64[8*120*3584] (27.5 MB) | fxy half2[B*HW] (9.83 MB)
    //   | counters u32[960] -> total ~37.4 MB
    unsigned long long* arena = (unsigned long long*)d_ws;
    __half2* fxy = (__half2*)((char*)d_ws +
                              (size_t)BB * NSL * STRIDE * sizeof(unsigned long long));
    unsigned int* counters = (unsigned int*)((char*)fxy +
                              (size_t)BB * HWSZ * sizeof(__half2));

    hipMemsetAsync(out, 0, sizeof(float), stream);

    flow_prep<<<1024, 256, 0, stream>>>(flow, fxy, out);

    const int pBlocks = BB * BPB;    // 784
    const int aBlocks = BB * NSL;    // 960

    for (int t = 0; t < 2; ++t) {
        float tref = (t == 0) ? 1.0f : 0.0f;
        hipMemsetAsync(counters, 0, BB * NSL * sizeof(unsigned int), stream);
        warp_place<<<pBlocks, 256, 0, stream>>>(ev, fxy, counters, arena, tref);
        slice_accum<<<aBlocks, 512, 0, stream>>>(arena, counters, out);
    }
}

// Round 7
// 144.872 us; speedup vs baseline: 7.1081x; 1.1397x over previous
//
#include <hip/hip_runtime.h>
#include <hip/hip_fp16.h>

#define BB 8
#define NN 200000
#define HH 480
#define WW 640
#define HWSZ (HH * WW)
#define BH 4                        // rows per slice
#define NSL (HH / BH)               // 120 slices
#define STRIDE 3584                 // arena slots per (b,slice); mean ~2083
#define AE ((size_t)BB * NSL * STRIDE)   // arena elements per tref

// dual-pass kernels
#define EPB2 1024
#define BPB2 ((NN + EPB2 - 1) / EPB2)    // 196
// sequential fallback kernels
#define EPB 2048
#define BPB ((NN + EPB - 1) / EPB)       // 98

// ---------------------------------------------------------------------------
// K0: flow interleave (f32x2 -> half2) fused with Charbonnier smoothness.
// ---------------------------------------------------------------------------
__global__ void __launch_bounds__(256) flow_prep(
        const float* __restrict__ flow, __half2* __restrict__ fxy,
        float* __restrict__ out) {
    const int total = BB * HWSZ;
    float s = 0.0f;
    for (int i = blockIdx.x * 256 + threadIdx.x; i < total;
         i += gridDim.x * 256) {
        int b = i / HWSZ, pix = i % HWSZ;
        const float* fb = flow + (size_t)b * 2 * HWSZ;
        float f0 = fb[pix], f1 = fb[HWSZ + pix];
        fxy[i] = __floats2half2_rn(f0, f1);
        int w = pix % WW, h = pix / WW;
        if (h < HH - 1) {
            float d0 = f0 - fb[pix + WW];
            float d1 = f1 - fb[HWSZ + pix + WW];
            s += sqrtf(d0 * d0 + 1e-6f) + sqrtf(d1 * d1 + 1e-6f);
        }
        if (w < WW - 1) {
            float d0 = f0 - fb[pix + 1];
            float d1 = f1 - fb[HWSZ + pix + 1];
            s += sqrtf(d0 * d0 + 1e-6f) + sqrtf(d1 * d1 + 1e-6f);
        }
    }
    #pragma unroll
    for (int off = 32; off > 0; off >>= 1)
        s += __shfl_down(s, off, 64);
    __shared__ float ls[4];
    int lane = threadIdx.x & 63, wid = threadIdx.x >> 6;
    if (lane == 0) ls[wid] = s;
    __syncthreads();
    if (threadIdx.x == 0)
        atomicAdd(out, ls[0] + ls[1] + ls[2] + ls[3]);
}

// ---------------------------------------------------------------------------
// K1-dual: warp each event for BOTH trefs in one pass; per-tref LDS hist;
// one global atomicAdd per touched (tref,slice); packed 8B payloads.
// payload: [qy:20 @38][qx:21 @17][pol:1 @16][qt:16 @0], coords (v+2)*2048.
// ---------------------------------------------------------------------------
__global__ void __launch_bounds__(256) warp_place_dual(
        const float4* __restrict__ ev, const __half2* __restrict__ fxy,
        unsigned int* __restrict__ counters,
        unsigned long long* __restrict__ arena) {
    __shared__ unsigned int h[2][NSL];
    __shared__ unsigned int bases[2][NSL];
    int b     = blockIdx.x & 7;            // XCD-affinity: batch b -> XCD b
    int chunk = blockIdx.x >> 3;
    if (threadIdx.x < 2 * NSL) h[threadIdx.x / NSL][threadIdx.x % NSL] = 0;
    __syncthreads();

    const float4*  evb = ev  + (size_t)b * NN;
    const __half2* fb  = fxy + (size_t)b * HWSZ;
    int base = chunk * EPB2;

    unsigned long long pay[2][4];
    unsigned short code[2][4];             // 0 invalid; else (s0+1) | dual<<8
    #pragma unroll
    for (int k = 0; k < 4; ++k) {
        code[0][k] = 0; code[1][k] = 0;
        int e = base + k * 256 + threadIdx.x;
        if (e < NN) {
            float4 E = evb[e];
            int gpix = (int)(E.y * 640.0f + E.z);
            float2 f = __half22float2(fb[gpix]);
            unsigned int pol = (E.w < 0.0f) ? 1u : 0u;
            #pragma unroll
            for (int t = 0; t < 2; ++t) {
                float tref = (t == 0) ? 1.0f : 0.0f;
                float dt = tref - E.x;
                float wy = fmaf(dt * f.y, 640.0f, E.y);   // flow_scaling=640
                float wx = fmaf(dt * f.x, 640.0f, E.z);
                if (wx >= -1.0f && wx < 640.0f && wy >= -2.0f && wy < 481.0f) {
                    int ity = (int)floorf(wy);
                    int r1 = ity + 1;
                    bool v0 = (ity >= 0) && (ity < HH);
                    bool v1 = (r1  >= 0) && (r1  < HH);
                    int s0 = -1; bool dual = false;
                    if (v0) { s0 = ity >> 2; dual = v1 && ((r1 >> 2) != s0); }
                    else if (v1) s0 = r1 >> 2;
                    if (s0 >= 0) {
                        code[t][k] = (unsigned short)((s0 + 1) | (dual ? 0x100 : 0));
                        float tw = (t == 0) ? E.x : (1.0f - E.x);
                        unsigned int qy = (unsigned int)((wy + 2.0f) * 2048.0f);
                        unsigned int qx = (unsigned int)((wx + 2.0f) * 2048.0f);
                        unsigned int qt = (unsigned int)fmaf(tw, 65535.0f, 0.5f);
                        pay[t][k] = ((unsigned long long)qy << 38)
                                  | ((unsigned long long)qx << 17)
                                  | ((unsigned long long)pol << 16)
                                  | (unsigned long long)qt;
                        atomicAdd(&h[t][s0], 1u);
                        if (dual) atomicAdd(&h[t][s0 + 1], 1u);
                    }
                }
            }
        }
    }
    __syncthreads();
    if (threadIdx.x < 2 * NSL) {           // 240 < 256
        int t = threadIdx.x / NSL, s = threadIdx.x % NSL;
        unsigned int c = h[t][s];
        bases[t][s] = c ? atomicAdd(&counters[(t * BB + b) * NSL + s], c) : 0u;
        h[t][s] = 0;                       // reuse as within-block cursor
    }
    __syncthreads();
    #pragma unroll
    for (int t = 0; t < 2; ++t) {
        unsigned long long* at = arena + (size_t)t * AE + (size_t)b * NSL * STRIDE;
        #pragma unroll
        for (int k = 0; k < 4; ++k) {
            unsigned int c = code[t][k];
            if (c) {
                int s = (int)(c & 0xff) - 1;
                unsigned int off = bases[t][s] + atomicAdd(&h[t][s], 1u);
                if (off < STRIDE) at[(size_t)s * STRIDE + off] = pay[t][k];
                if (c & 0x100) {
                    off = bases[t][s + 1] + atomicAdd(&h[t][s + 1], 1u);
                    if (off < STRIDE) at[(size_t)(s + 1) * STRIDE + off] = pay[t][k];
                }
            }
        }
    }
}

// ---------------------------------------------------------------------------
// Shared accumulate body: one (b,slice,tref) bucket -> LDS half2 accumulate
// via ds_pk_add_f16, fused ratio-square reduce, one global atomic.
// ---------------------------------------------------------------------------
__device__ __forceinline__ void accum_body(
        const unsigned long long* __restrict__ cell, unsigned int cnt, int r0,
        float* __restrict__ out) {
    __shared__ __half2 acc[BH * WW * 2];   // [row][col][pol] {w,wt} = 20 KB
    for (int i = threadIdx.x; i < BH * WW * 2; i += 512)
        acc[i] = __half2(__float2half(0.0f), __float2half(0.0f));
    __syncthreads();

    for (unsigned int i = threadIdx.x; i < cnt; i += 512) {
        unsigned long long p = cell[i];
        float tw = (float)(unsigned int)(p & 0xFFFFu) * (1.0f / 65535.0f);
        int  pol = (int)((p >> 16) & 1u);
        float wx = (float)(unsigned int)((p >> 17) & 0x1FFFFFu) * (1.0f / 2048.0f) - 2.0f;
        float wy = (float)(unsigned int)((p >> 38) & 0xFFFFFu)  * (1.0f / 2048.0f) - 2.0f;
        float fy = floorf(wy), fx = floorf(wx);
        float ry = wy - fy,    rx = wx - fx;
        int ity = (int)fy, ilx = (int)fx;
        #pragma unroll
        for (int dy = 0; dy < 2; ++dy) {
            int r = ity + dy;
            if (r < r0 || r >= r0 + BH) continue;   // clip rows to slice
            float wyw = dy ? ry : 1.0f - ry;
            #pragma unroll
            for (int dx = 0; dx < 2; ++dx) {
                int ix = ilx + dx;
                if (ix < 0 || ix >= WW) continue;
                float wgt = wyw * (dx ? rx : 1.0f - rx);
                int a = ((r - r0) * WW + ix) * 2 + pol;
                unsafeAtomicAdd(&acc[a], __floats2half2_rn(wgt, wgt * tw));
            }
        }
    }
    __syncthreads();

    float sum = 0.0f;
    for (int i = threadIdx.x; i < BH * WW * 2; i += 512) {
        float2 v = __half22float2(acc[i]);
        float r = v.y / (v.x + 1e-9f);
        sum += r * r;
    }
    #pragma unroll
    for (int off = 32; off > 0; off >>= 1)
        sum += __shfl_down(sum, off, 64);
    __shared__ float ls[8];
    int lane = threadIdx.x & 63, wid = threadIdx.x >> 6;
    if (lane == 0) ls[wid] = sum;
    __syncthreads();
    if (threadIdx.x == 0) {
        float tot = 0.0f;
        #pragma unroll
        for (int k = 0; k < 8; ++k) tot += ls[k];
        atomicAdd(out, tot);
    }
}

// K2-dual: grid = BB * NSL * 2; both trefs in one launch.
__global__ void __launch_bounds__(512) slice_accum_dual(
        const unsigned long long* __restrict__ arena,
        const unsigned int* __restrict__ counters, float* __restrict__ out) {
    int b = blockIdx.x & 7;                // XCD-affinity
    int rest = blockIdx.x >> 3;            // 0..239
    int t = rest & 1;
    int s = rest >> 1;
    unsigned int cnt = counters[(t * BB + b) * NSL + s];
    if (cnt > STRIDE) cnt = STRIDE;
    const unsigned long long* cell =
        arena + (size_t)t * AE + ((size_t)(b * NSL + s)) * STRIDE;
    accum_body(cell, cnt, s * BH, out);
}

// ---------------------------------------------------------------------------
// Sequential fallback (R5 path), used when ws_size < dual requirement.
// ---------------------------------------------------------------------------
__global__ void __launch_bounds__(256) warp_place(
        const float4* __restrict__ ev, const __half2* __restrict__ fxy,
        unsigned int* __restrict__ counters,
        unsigned long long* __restrict__ arena, float tref) {
    __shared__ unsigned int h[NSL];
    __shared__ unsigned int bases[NSL];
    int b     = blockIdx.x & 7;
    int chunk = blockIdx.x >> 3;
    for (int i = threadIdx.x; i < NSL; i += 256) h[i] = 0;
    __syncthreads();

    const float4*  evb = ev  + (size_t)b * NN;
    const __half2* fb  = fxy + (size_t)b * HWSZ;
    int base = chunk * EPB;

    unsigned long long pay[8];
    int code[8];
    #pragma unroll
    for (int k = 0; k < 8; ++k) {
        code[k] = 0;
        int e = base + k * 256 + threadIdx.x;
        if (e < NN) {
            float4 E = evb[e];
            int gpix = (int)(E.y * 640.0f + E.z);
            float2 f = __half22float2(fb[gpix]);
            float dt = tref - E.x;
            float wy = fmaf(dt * f.y, 640.0f, E.y);
            float wx = fmaf(dt * f.x, 640.0f, E.z);
            if (wx >= -1.0f && wx < 640.0f && wy >= -2.0f && wy < 481.0f) {
                int ity = (int)floorf(wy);
                int r1 = ity + 1;
                bool v0 = (ity >= 0) && (ity < HH);
                bool v1 = (r1  >= 0) && (r1  < HH);
                int s0 = -1; bool dual = false;
                if (v0) { s0 = ity >> 2; dual = v1 && ((r1 >> 2) != s0); }
                else if (v1) s0 = r1 >> 2;
                if (s0 >= 0) {
                    code[k] = (s0 + 1) | (dual ? 0x100 : 0);
                    float tw = (tref == 1.0f) ? E.x : (1.0f - E.x);
                    unsigned int pol = (E.w < 0.0f) ? 1u : 0u;
                    unsigned int qy = (unsigned int)((wy + 2.0f) * 2048.0f);
                    unsigned int qx = (unsigned int)((wx + 2.0f) * 2048.0f);
                    unsigned int qt = (unsigned int)fmaf(tw, 65535.0f, 0.5f);
                    pay[k] = ((unsigned long long)qy << 38)
                           | ((unsigned long long)qx << 17)
                           | ((unsigned long long)pol << 16)
                           | (unsigned long long)qt;
                    atomicAdd(&h[s0], 1u);
                    if (dual) atomicAdd(&h[s0 + 1], 1u);
                }
            }
        }
    }
    __syncthreads();
    for (int s = threadIdx.x; s < NSL; s += 256) {
        unsigned int c = h[s];
        bases[s] = c ? atomicAdd(&counters[b * NSL + s], c) : 0u;
        h[s] = 0;
    }
    __syncthreads();
    #pragma unroll
    for (int k = 0; k < 8; ++k) {
        if (code[k]) {
            int s = (code[k] & 0xff) - 1;
            unsigned int off = bases[s] + atomicAdd(&h[s], 1u);
            if (off < STRIDE)
                arena[((size_t)(b * NSL + s)) * STRIDE + off] = pay[k];
            if (code[k] & 0x100) {
                off = bases[s + 1] + atomicAdd(&h[s + 1], 1u);
                if (off < STRIDE)
                    arena[((size_t)(b * NSL + s + 1)) * STRIDE + off] = pay[k];
            }
        }
    }
}

__global__ void __launch_bounds__(512) slice_accum(
        const unsigned long long* __restrict__ arena,
        const unsigned int* __restrict__ counters, float* __restrict__ out) {
    int b = blockIdx.x & 7;
    int s = blockIdx.x >> 3;
    unsigned int cnt = counters[b * NSL + s];
    if (cnt > STRIDE) cnt = STRIDE;
    const unsigned long long* cell = arena + ((size_t)(b * NSL + s)) * STRIDE;
    accum_body(cell, cnt, s * BH, out);
}

extern "C" void kernel_launch(void* const* d_in, const int* in_sizes, int n_in,
                              void* d_out, int out_size, void* d_ws, size_t ws_size,
                              hipStream_t stream) {
    const float*  flow = (const float*)d_in[0];   // [B,2,H,W]
    const float4* ev   = (const float4*)d_in[1];  // [B,N,4]
    float* out = (float*)d_out;

    const size_t arena_bytes = AE * sizeof(unsigned long long);   // 27.5 MB
    const size_t fxy_bytes   = (size_t)BB * HWSZ * sizeof(__half2); // 9.83 MB
    const size_t need_dual   = 2 * arena_bytes + fxy_bytes + 2 * BB * NSL * 4;
    const bool dual = (ws_size >= need_dual);

    unsigned long long* arena = (unsigned long long*)d_ws;
    __half2* fxy = (__half2*)((char*)d_ws + (dual ? 2 : 1) * arena_bytes);
    unsigned int* counters = (unsigned int*)((char*)fxy + fxy_bytes);

    hipMemsetAsync(out, 0, sizeof(float), stream);
    flow_prep<<<1024, 256, 0, stream>>>(flow, fxy, out);

    if (dual) {
        hipMemsetAsync(counters, 0, 2 * BB * NSL * sizeof(unsigned int), stream);
        warp_place_dual<<<8 * BPB2, 256, 0, stream>>>(ev, fxy, counters, arena);
        slice_accum_dual<<<8 * (NSL * 2), 512, 0, stream>>>(arena, counters, out);
    } else {
        for (int t = 0; t < 2; ++t) {
            float tref = (t == 0) ? 1.0f : 0.0f;
            hipMemsetAsync(counters, 0, BB * NSL * sizeof(unsigned int), stream);
            warp_place<<<8 * BPB, 256, 0, stream>>>(ev, fxy, counters, arena, tref);
            slice_accum<<<8 * NSL, 512, 0, stream>>>(arena, counters, out);
        }
    }
}